// Round 4
// baseline (7790.449 us; speedup 1.0000x reference)
//
#include <hip/hip_runtime.h>

#define V_  50000
#define E_  384
#define H_  256
#define B_  64
#define TD_ 1024
#define TQ_ 32
#define G3_ 768   // 3*H
#define G6_ 1536  // both dirs
#define HH2_ 512  // 2*H

typedef unsigned short u16t;
typedef __attribute__((ext_vector_type(8))) short short8;
typedef __attribute__((ext_vector_type(4))) float float4v;

__device__ __forceinline__ float b2f(u16t u) {
    unsigned int i = ((unsigned int)u) << 16;
    float f; __builtin_memcpy(&f, &i, 4); return f;
}
__device__ __forceinline__ u16t f2b(float f) {   // round-to-nearest-even bf16
    unsigned int i; __builtin_memcpy(&i, &f, 4);
    unsigned int r = i + 0x7fffu + ((i >> 16) & 1u);
    return (u16t)(r >> 16);
}
__device__ __forceinline__ float sigm(float x) { return 1.0f / (1.0f + __expf(-x)); }
__device__ __forceinline__ float tanh_fast(float x) { return 1.0f - 2.0f / (__expf(2.0f * x) + 1.0f); }

// ---------------------------------------------------------------------------
// K0: fp32 -> bf16 conversion (inputs are fp32; MFMA needs bf16)
// ---------------------------------------------------------------------------
__global__ __launch_bounds__(256) void k_f2b(
    const float* __restrict__ src, u16t* __restrict__ dst, int n4)
{
    const int i = blockIdx.x * 256 + threadIdx.x;
    if (i < n4) {
        float4v v = *(const float4v*)(src + (size_t)i * 4);
        u16t o[4];
#pragma unroll
        for (int k = 0; k < 4; ++k) o[k] = f2b(v[k]);
        *(unsigned long long*)(dst + (size_t)i * 4) = *(unsigned long long*)o;
    }
}

// ---------------------------------------------------------------------------
// K1: xw[row][c] = emb[tok[row]] . W{f,b}[c] + bih   (c in [0,1536): f then b)
// tile: 64 rows x 128 cols per WG; 4 waves each 64x32.
// ---------------------------------------------------------------------------
__global__ __launch_bounds__(256) void k_xw(
    const int* __restrict__ tokens, const u16t* __restrict__ emb,
    const u16t* __restrict__ Wf, const u16t* __restrict__ Wb,
    const float* __restrict__ bf, const float* __restrict__ bb,
    u16t* __restrict__ xw)
{
    const int wave = threadIdx.x >> 6, lane = threadIdx.x & 63;
    const int quad = lane >> 4, l = lane & 15;
    const int rb = blockIdx.y * 64, cb = blockIdx.x * 128;
    const int c0 = cb + wave * 32;

    int tok[4];
#pragma unroll
    for (int mt = 0; mt < 4; ++mt) tok[mt] = tokens[rb + mt * 16 + l];

    float4v acc[4][2] = {};
#pragma unroll
    for (int kc = 0; kc < 12; ++kc) {
        const int ko = kc * 32 + quad * 8;
        short8 a[4];
#pragma unroll
        for (int mt = 0; mt < 4; ++mt)
            a[mt] = *(const short8*)(emb + (size_t)tok[mt] * E_ + ko);
#pragma unroll
        for (int nt = 0; nt < 2; ++nt) {
            const int c = c0 + nt * 16 + l;
            const u16t* wp = (c < G3_) ? (Wf + (size_t)c * E_) : (Wb + (size_t)(c - G3_) * E_);
            short8 b = *(const short8*)(wp + ko);
#pragma unroll
            for (int mt = 0; mt < 4; ++mt)
                acc[mt][nt] = __builtin_amdgcn_mfma_f32_16x16x32_bf16(a[mt], b, acc[mt][nt], 0, 0, 0);
        }
    }
#pragma unroll
    for (int nt = 0; nt < 2; ++nt) {
        const int c = c0 + nt * 16 + l;
        const float bias = (c < G3_) ? bf[c] : bb[c - G3_];
#pragma unroll
        for (int mt = 0; mt < 4; ++mt)
#pragma unroll
            for (int rr = 0; rr < 4; ++rr) {
                const int row = rb + mt * 16 + quad * 4 + rr;
                xw[(size_t)row * G6_ + c] = f2b(acc[mt][nt][rr] + bias);
            }
    }
}

// ---------------------------------------------------------------------------
// K2: GRU recurrence. 16 WGs x 512 thr. WG = {doc|qry} x dir x 16-sample block.
// Per step: hh = h @ Whh^T via MFMA (M=16 samples, N=768 gates, K=256),
// then gates + state update; h kept fp32 in regs, bf16 copy in LDS for MFMA A.
// ---------------------------------------------------------------------------
__global__ __launch_bounds__(512) void k_gru(
    const u16t* __restrict__ xw_doc, const u16t* __restrict__ xw_qry,
    const u16t* __restrict__ Whh_f, const u16t* __restrict__ Whh_b,
    const float* __restrict__ bhh_f, const float* __restrict__ bhh_b,
    const int* __restrict__ doc_lens, const int* __restrict__ qry_lens,
    u16t* __restrict__ doc_h, u16t* __restrict__ qry_h)
{
    __shared__ u16t hb[2][16][264];   // +8 bf16 pad: 16B-aligned rows

    const int wid = blockIdx.x;
    const bool isDoc = wid < 8;
    const int local = isDoc ? wid : wid - 8;
    const int dir = local >> 2;            // 0 fwd, 1 bwd
    const int s0 = (local & 3) * 16;
    const int T = isDoc ? TD_ : TQ_;
    const u16t* xw = isDoc ? xw_doc : xw_qry;
    u16t* outH = isDoc ? doc_h : qry_h;
    const int* lens = isDoc ? doc_lens : qry_lens;
    const u16t* Whh = dir ? Whh_b : Whh_f;
    const float* bhh = dir ? bhh_b : bhh_f;

    const int tid = threadIdx.x;
    const int wave = tid >> 6, lane = tid & 63, quad = lane >> 4, l = lane & 15;

    for (int idx = tid; idx < 16 * 264; idx += 512) ((u16t*)hb[0])[idx] = 0;

    // tiles nt: 0,1 -> r ; 2,3 -> z ; 4,5 -> n.  gate col = (nt>>1)*256 + wave*32 + (nt&1)*16 + l
    int cn[6]; float bh[6];
#pragma unroll
    for (int nt = 0; nt < 6; ++nt) {
        cn[nt] = (nt >> 1) * 256 + wave * 32 + (nt & 1) * 16 + l;
        bh[nt] = bhh[cn[nt]];
    }
    int len4[4]; size_t rowbase[4];
#pragma unroll
    for (int rr = 0; rr < 4; ++rr) {
        const int sl = quad * 4 + rr;
        len4[rr] = lens[s0 + sl];
        rowbase[rr] = (size_t)(s0 + sl) * T;
    }
    float hreg[2][4] = {};
    __syncthreads();

    for (int i = 0; i < T; ++i) {
        const int buf = i & 1;
        short8 a[8];
#pragma unroll
        for (int kc = 0; kc < 8; ++kc)
            a[kc] = *(const short8*)&hb[buf][l][kc * 32 + quad * 8];

        float4v acc[6] = {};
#pragma unroll
        for (int nt = 0; nt < 6; ++nt) {
            const u16t* wp = Whh + (size_t)cn[nt] * H_ + quad * 8;
#pragma unroll
            for (int kc = 0; kc < 8; ++kc) {
                short8 b = *(const short8*)(wp + kc * 32);
                acc[nt] = __builtin_amdgcn_mfma_f32_16x16x32_bf16(a[kc], b, acc[nt], 0, 0, 0);
            }
        }
#pragma unroll
        for (int rr = 0; rr < 4; ++rr) {
            const int sl = quad * 4 + rr;
            const bool valid = i < len4[rr];
            const int pos = dir ? (valid ? (len4[rr] - 1 - i) : 0) : i;
            const u16t* xr = xw + (rowbase[rr] + pos) * G6_ + dir * G3_;
#pragma unroll
            for (int jt = 0; jt < 2; ++jt) {
                const int jv = wave * 32 + jt * 16 + l;
                const float gr = b2f(xr[jv])        + acc[jt][rr]     + bh[jt];
                const float gz = b2f(xr[256 + jv])  + acc[2 + jt][rr] + bh[2 + jt];
                const float r = sigm(gr), z = sigm(gz);
                const float nn = tanh_fast(b2f(xr[512 + jv]) + r * (acc[4 + jt][rr] + bh[4 + jt]));
                const float h = (1.0f - z) * nn + z * hreg[jt][rr];
                hreg[jt][rr] = h;
                const u16t hb16 = f2b(h);
                hb[1 - buf][sl][jv] = hb16;
                if (valid)
                    outH[(rowbase[rr] + pos) * HH2_ + dir * H_ + jv] = hb16;
            }
        }
        __syncthreads();
    }
}

// ---------------------------------------------------------------------------
// K3: scores[s][d][q] = doc_h[s][d] . qry_h[s][q]  (fp32 out). WG per sample.
// ---------------------------------------------------------------------------
__global__ __launch_bounds__(256) void k_scores(
    const u16t* __restrict__ doc_h, const u16t* __restrict__ qry_h,
    float* __restrict__ scores)
{
    __shared__ u16t qh[32 * 520];   // [q][k] padded
    const int s = blockIdx.x;
    const int tid = threadIdx.x, wave = tid >> 6, lane = tid & 63;
    const int quad = lane >> 4, l = lane & 15;

#pragma unroll
    for (int it = 0; it < 8; ++it) {
        const int v = tid + it * 256;
        const int flat = v * 8, q = flat >> 9, k = flat & 511;
        *(short8*)&qh[q * 520 + k] = *(const short8*)(qry_h + ((size_t)s * TQ_ + q) * HH2_ + k);
    }
    __syncthreads();

    for (int mt = 0; mt < 16; ++mt) {
        const int d0 = wave * 256 + mt * 16;
        float4v a0 = {}, a1 = {};
        const u16t* dp = doc_h + ((size_t)s * TD_ + d0 + l) * HH2_;
#pragma unroll
        for (int kc = 0; kc < 16; ++kc) {
            const int ko = kc * 32 + quad * 8;
            short8 a = *(const short8*)(dp + ko);
            short8 b0 = *(const short8*)&qh[l * 520 + ko];
            short8 b1 = *(const short8*)&qh[(16 + l) * 520 + ko];
            a0 = __builtin_amdgcn_mfma_f32_16x16x32_bf16(a, b0, a0, 0, 0, 0);
            a1 = __builtin_amdgcn_mfma_f32_16x16x32_bf16(a, b1, a1, 0, 0, 0);
        }
        float* sp = scores + ((size_t)s * TD_ + d0) * TQ_;
#pragma unroll
        for (int rr = 0; rr < 4; ++rr) {
            const int d = quad * 4 + rr;
            sp[(size_t)d * TQ_ + l] = a0[rr];
            sp[(size_t)d * TQ_ + 16 + l] = a1[rr];
        }
    }
}

// ---------------------------------------------------------------------------
// K4: per (s,q): amax = max_d scores (raw, incl. exact-0 invalid entries),
//     aden = sum_d exp(sc-amax)*pair_mask + EPS.
// ---------------------------------------------------------------------------
__global__ __launch_bounds__(1024) void k_alpha(
    const float* __restrict__ scores, const int* __restrict__ doc_lens,
    const int* __restrict__ qry_lens, float* __restrict__ amax_g, float* __restrict__ aden_g)
{
    __shared__ float red[32 * 33];
    const int s = blockIdx.x, tid = threadIdx.x;
    const int q = tid & 31, dg = tid >> 5;
    const float* sp = scores + (size_t)s * TD_ * TQ_;

    float m = -1e30f;
#pragma unroll 4
    for (int k = 0; k < 32; ++k) m = fmaxf(m, sp[(size_t)(dg + k * 32) * TQ_ + q]);
    red[q * 33 + dg] = m; __syncthreads();
    for (int off = 16; off > 0; off >>= 1) {
        if (dg < off) red[q * 33 + dg] = fmaxf(red[q * 33 + dg], red[q * 33 + dg + off]);
        __syncthreads();
    }
    const float mx = red[q * 33];
    __syncthreads();

    const int dlen = doc_lens[s], qlen = qry_lens[s];
    float sum = 0.0f;
    if (q < qlen) {
#pragma unroll 4
        for (int k = 0; k < 32; ++k) {
            const int d = dg + k * 32;
            if (d < dlen) sum += __expf(sp[(size_t)d * TQ_ + q] - mx);
        }
    }
    red[q * 33 + dg] = sum; __syncthreads();
    for (int off = 16; off > 0; off >>= 1) {
        if (dg < off) red[q * 33 + dg] += red[q * 33 + dg + off];
        __syncthreads();
    }
    if (dg == 0) {
        amax_g[s * 32 + q] = mx;
        aden_g[s * 32 + q] = red[q * 33] + 1e-12f;
    }
}

// ---------------------------------------------------------------------------
// K5: beta softmax (axis=q), beta_aver, s_d, probs, vocab scatter. WG per sample.
// probs written as FP32 to out[s].
// ---------------------------------------------------------------------------
__global__ __launch_bounds__(1024) void k_attn(
    const float* __restrict__ scores, const int* __restrict__ documents,
    const int* __restrict__ doc_lens, const int* __restrict__ qry_lens,
    const int* __restrict__ answers,
    const float* __restrict__ amax_g, const float* __restrict__ aden_g,
    float* __restrict__ wordbuf, float* __restrict__ out_f)
{
    __shared__ float l_amax[32], l_aden[32], l_ba[32];
    __shared__ float l_probs;
    const int s = blockIdx.x, d = threadIdx.x;
    if (d < 32) { l_amax[d] = amax_g[s * 32 + d]; l_aden[d] = aden_g[s * 32 + d]; l_ba[d] = 0.0f; }
    if (d == 0) l_probs = 0.0f;
    __syncthreads();

    const int dlen = doc_lens[s], qlen = qry_lens[s];
    const bool maskd = d < dlen;
    float raw[32];
    const float* sp = scores + ((size_t)s * TD_ + d) * TQ_;
#pragma unroll
    for (int q = 0; q < 32; q += 4) {
        float4v v = *(const float4v*)(sp + q);
        raw[q] = v[0]; raw[q + 1] = v[1]; raw[q + 2] = v[2]; raw[q + 3] = v[3];
    }
    float rowmax = raw[0];
#pragma unroll
    for (int q = 1; q < 32; ++q) rowmax = fmaxf(rowmax, raw[q]);

    float den = 1e-12f;
    if (maskd)
        for (int q = 0; q < qlen; ++q) den += __expf(raw[q] - rowmax);

    // beta_aver accumulation: wave butterfly then one LDS atomic per wave
#pragma unroll
    for (int q = 0; q < 32; ++q) {
        float beta = (maskd && q < qlen) ? __expf(raw[q] - rowmax) / den : 0.0f;
#pragma unroll
        for (int off = 1; off < 64; off <<= 1) beta += __shfl_xor(beta, off);
        if ((threadIdx.x & 63) == 0 && beta != 0.0f) atomicAdd(&l_ba[q], beta);
    }
    __syncthreads();

    float sd = 0.0f;
    if (maskd) {
        const float inv_dlen = 1.0f / (float)dlen;
        for (int q = 0; q < qlen; ++q) {
            const float ae = __expf(raw[q] - l_amax[q]) / l_aden[q];  // exponent <= 0, safe
            sd += ae * (l_ba[q] * inv_dlen);
        }
    }
    const int tok = documents[s * TD_ + d];
    float p = (tok == answers[s]) ? sd : 0.0f;
#pragma unroll
    for (int off = 1; off < 64; off <<= 1) p += __shfl_xor(p, off);
    if ((threadIdx.x & 63) == 0 && p != 0.0f) atomicAdd(&l_probs, p);
    if (maskd && sd != 0.0f) atomicAdd(wordbuf + (size_t)s * V_ + tok, sd);
    __syncthreads();
    if (threadIdx.x == 0) out_f[s] = l_probs;
}

// ---------------------------------------------------------------------------
// K6: per-sample argmax over vocab (zero-init; all sums >= 0, some > 0 ->
// equals reference's cnts>0 ? sums : -1e30 argmax). Lowest-idx tie-break.
// Index written as FP32 to out[64+s].
// ---------------------------------------------------------------------------
__global__ __launch_bounds__(256) void k_argmax(
    const float* __restrict__ wordbuf, float* __restrict__ out_f)
{
    __shared__ float bv[256];
    __shared__ int bi[256];
    const int s = blockIdx.x, tid = threadIdx.x;
    const float* wp = wordbuf + (size_t)s * V_;
    float best = -1e30f; int bidx = 0;
    for (int v = tid; v < V_; v += 256) {
        const float f = wp[v];
        if (f > best) { best = f; bidx = v; }
    }
    bv[tid] = best; bi[tid] = bidx; __syncthreads();
    for (int off = 128; off > 0; off >>= 1) {
        if (tid < off) {
            const float fo = bv[tid + off]; const int io = bi[tid + off];
            if (fo > bv[tid] || (fo == bv[tid] && io < bi[tid])) { bv[tid] = fo; bi[tid] = io; }
        }
        __syncthreads();
    }
    if (tid == 0) out_f[64 + s] = (float)bi[0];
}

// ---------------------------------------------------------------------------
// Workspace layout (peak 277.6 MB):
//   [A] Whh_f16, Whh_b16 (0.78 MB, live whole run)
//   [B] doc_h (67.1 MB) + qry_h (2.1 MB)
//        -- head aliased EARLY by emb_b16 (38.4) + Wih_f16/b16 (2.36);
//           doc_h/qry_h zeroed AFTER k_xw.
//   [C] xw_qry (6.3 MB), xw_doc (201.3 MB)
//        -- head of xw_doc aliased LATE by scores (8.4) + amax/aden + wordbuf
//           (12.8); wordbuf zeroed after k_gru.
// ---------------------------------------------------------------------------
extern "C" void kernel_launch(void* const* d_in, const int* in_sizes, int n_in,
                              void* d_out, int out_size, void* d_ws, size_t ws_size,
                              hipStream_t stream)
{
    const int*   documents  = (const int*)d_in[0];
    const int*   doc_lens   = (const int*)d_in[1];
    const int*   querys     = (const int*)d_in[2];
    const int*   query_lens = (const int*)d_in[3];
    const int*   answers    = (const int*)d_in[4];
    const float* emb_f32    = (const float*)d_in[5];
    const float* Wih_f_f32  = (const float*)d_in[6];
    const float* Whh_f_f32  = (const float*)d_in[7];
    const float* bih_f      = (const float*)d_in[8];
    const float* bhh_f      = (const float*)d_in[9];
    const float* Wih_b_f32  = (const float*)d_in[10];
    const float* Whh_b_f32  = (const float*)d_in[11];
    const float* bih_b      = (const float*)d_in[12];
    const float* bhh_b      = (const float*)d_in[13];
    float* out = (float*)d_out;   // fp32: [probs(64), pred_answers(64)]
    char* ws = (char*)d_ws;

    size_t o = 0;
    u16t* Whh_f16 = (u16t*)(ws + o); o += (size_t)G3_ * H_ * 2;
    u16t* Whh_b16 = (u16t*)(ws + o); o += (size_t)G3_ * H_ * 2;
    char* hblock = ws + o;
    u16t* doc_h = (u16t*)(ws + o); o += (size_t)B_ * TD_ * HH2_ * 2;     //  67.1 MB
    u16t* qry_h = (u16t*)(ws + o); o += (size_t)B_ * TQ_ * HH2_ * 2;     //   2.1 MB
    const size_t hbytes = (size_t)(ws + o - hblock);
    u16t* xw_qry = (u16t*)(ws + o); o += (size_t)B_ * TQ_ * G6_ * 2;     //   6.3 MB
    char* xdblock = ws + o;
    u16t* xw_doc = (u16t*)(ws + o); o += (size_t)B_ * TD_ * G6_ * 2;     // 201.3 MB
    const size_t total = o;                                              // 277.6 MB
    if (ws_size < total) return;  // clean stub signature instead of fault

    // early aliases (dead once k_xw completes): emb/Wih bf16 inside doc_h
    u16t* emb_b16   = (u16t*)hblock;
    u16t* Wih_f16   = (u16t*)(hblock + (size_t)V_ * E_ * 2);
    u16t* Wih_b16   = Wih_f16 + (size_t)G3_ * E_;
    // late aliases (live once xw_doc is dead, i.e. after k_gru):
    float* scores  = (float*)xdblock;
    float* amax    = (float*)(xdblock + (size_t)B_ * TD_ * TQ_ * 4);
    float* aden    = amax + B_ * 32;
    float* wordbuf = aden + B_ * 32;

    // 1) fp32 -> bf16 conversions
    const int n_emb4 = V_ * E_ / 4, n_wih4 = G3_ * E_ / 4, n_whh4 = G3_ * H_ / 4;
    k_f2b<<<(n_emb4 + 255) / 256, 256, 0, stream>>>(emb_f32, emb_b16, n_emb4);
    k_f2b<<<(n_wih4 + 255) / 256, 256, 0, stream>>>(Wih_f_f32, Wih_f16, n_wih4);
    k_f2b<<<(n_wih4 + 255) / 256, 256, 0, stream>>>(Wih_b_f32, Wih_b16, n_wih4);
    k_f2b<<<(n_whh4 + 255) / 256, 256, 0, stream>>>(Whh_f_f32, Whh_f16, n_whh4);
    k_f2b<<<(n_whh4 + 255) / 256, 256, 0, stream>>>(Whh_b_f32, Whh_b16, n_whh4);

    // 2) input projection GEMMs
    k_xw<<<dim3(12, (B_ * TD_) / 64), 256, 0, stream>>>(documents, emb_b16, Wih_f16, Wih_b16, bih_f, bih_b, xw_doc);
    k_xw<<<dim3(12, (B_ * TQ_) / 64), 256, 0, stream>>>(querys, emb_b16, Wih_f16, Wih_b16, bih_f, bih_b, xw_qry);

    // 3) alias dead: zero doc_h/qry_h (invalid positions must be exactly 0)
    hipMemsetAsync(hblock, 0, hbytes, stream);

    // 4) recurrence
    k_gru<<<16, 512, 0, stream>>>(xw_doc, xw_qry, Whh_f16, Whh_b16, bhh_f, bhh_b,
                                  doc_lens, query_lens, doc_h, qry_h);

    // 5) xw_doc dead: zero wordbuf alias, then attention chain
    hipMemsetAsync(wordbuf, 0, (size_t)B_ * V_ * 4, stream);
    k_scores<<<B_, 256, 0, stream>>>(doc_h, qry_h, scores);
    k_alpha<<<B_, 1024, 0, stream>>>(scores, doc_lens, query_lens, amax, aden);
    k_attn<<<B_, 1024, 0, stream>>>(scores, documents, doc_lens, query_lens, answers,
                                    amax, aden, wordbuf, out);
    k_argmax<<<B_, 256, 0, stream>>>(wordbuf, out);
}

// Round 6
// 4854.890 us; speedup vs baseline: 1.6047x; 1.6047x over previous
//
#include <hip/hip_runtime.h>

#define V_  50000
#define E_  384
#define H_  256
#define B_  64
#define TD_ 1024
#define TQ_ 32
#define G3_ 768   // 3*H
#define G6_ 1536  // both dirs
#define HH2_ 512  // 2*H

typedef unsigned short u16t;
typedef __attribute__((ext_vector_type(8))) short short8;
typedef __attribute__((ext_vector_type(4))) float float4v;

__device__ __forceinline__ float b2f(u16t u) {
    unsigned int i = ((unsigned int)u) << 16;
    float f; __builtin_memcpy(&f, &i, 4); return f;
}
__device__ __forceinline__ u16t f2b(float f) {   // round-to-nearest-even bf16
    unsigned int i; __builtin_memcpy(&i, &f, 4);
    unsigned int r = i + 0x7fffu + ((i >> 16) & 1u);
    return (u16t)(r >> 16);
}
__device__ __forceinline__ float sigm(float x) { return 1.0f / (1.0f + __expf(-x)); }
__device__ __forceinline__ float tanh_fast(float x) { return 1.0f - 2.0f / (__expf(2.0f * x) + 1.0f); }

// ---------------------------------------------------------------------------
// K0: fp32 -> bf16 conversion
// ---------------------------------------------------------------------------
__global__ __launch_bounds__(256) void k_f2b(
    const float* __restrict__ src, u16t* __restrict__ dst, int n4)
{
    const int i = blockIdx.x * 256 + threadIdx.x;
    if (i < n4) {
        float4v v = *(const float4v*)(src + (size_t)i * 4);
        u16t o[4];
#pragma unroll
        for (int k = 0; k < 4; ++k) o[k] = f2b(v[k]);
        *(unsigned long long*)(dst + (size_t)i * 4) = *(unsigned long long*)o;
    }
}

// ---------------------------------------------------------------------------
// K1: input projection, written TIME-MAJOR per direction:
//   xwt_f[t][s][c]    = emb[tok[s,t]].Wf[c] + bih_f[c] (+bhh_f[c] if c<512)
//   xwt_r[slot][s][c] = ... bwd, slot = (t<len)? len-1-t : t  (bijection)
// bhh fold valid for r/z gates only (n-gate bhh stays in k_gru inside r*()).
// ---------------------------------------------------------------------------
__global__ __launch_bounds__(256) void k_xw(
    const int* __restrict__ tokens, const u16t* __restrict__ emb,
    const u16t* __restrict__ Wf, const u16t* __restrict__ Wb,
    const float* __restrict__ bihf, const float* __restrict__ bihb,
    const float* __restrict__ bhhf, const float* __restrict__ bhhb,
    const int* __restrict__ lens, int tshift,
    u16t* __restrict__ xwt_f, u16t* __restrict__ xwt_r)
{
    const int wave = threadIdx.x >> 6, lane = threadIdx.x & 63;
    const int quad = lane >> 4, l = lane & 15;
    const int rb = blockIdx.y * 64, cb = blockIdx.x * 128;
    const int c0 = cb + wave * 32;
    const int tmask = (1 << tshift) - 1;

    int tok[4];
#pragma unroll
    for (int mt = 0; mt < 4; ++mt) tok[mt] = tokens[rb + mt * 16 + l];

    float4v acc[4][2] = {};
#pragma unroll
    for (int kc = 0; kc < 12; ++kc) {
        const int ko = kc * 32 + quad * 8;
        short8 a[4];
#pragma unroll
        for (int mt = 0; mt < 4; ++mt)
            a[mt] = *(const short8*)(emb + (size_t)tok[mt] * E_ + ko);
#pragma unroll
        for (int nt = 0; nt < 2; ++nt) {
            const int c = c0 + nt * 16 + l;
            const u16t* wp = (c < G3_) ? (Wf + (size_t)c * E_) : (Wb + (size_t)(c - G3_) * E_);
            short8 b = *(const short8*)(wp + ko);
#pragma unroll
            for (int mt = 0; mt < 4; ++mt)
                acc[mt][nt] = __builtin_amdgcn_mfma_f32_16x16x32_bf16(a[mt], b, acc[mt][nt], 0, 0, 0);
        }
    }
#pragma unroll
    for (int nt = 0; nt < 2; ++nt) {
        const int c = c0 + nt * 16 + l;
        const bool fwd = (c < G3_);
        const int cg = fwd ? c : c - G3_;
        const float bias = (fwd ? bihf[cg] : bihb[cg]) +
                           ((cg < 512) ? (fwd ? bhhf[cg] : bhhb[cg]) : 0.0f);
        u16t* xwt = fwd ? xwt_f : xwt_r;
#pragma unroll
        for (int mt = 0; mt < 4; ++mt)
#pragma unroll
            for (int rr = 0; rr < 4; ++rr) {
                const int row = rb + mt * 16 + quad * 4 + rr;
                const int s = row >> tshift, t = row & tmask;
                int slot = t;
                if (!fwd) { const int len = lens[s]; slot = (t < len) ? (len - 1 - t) : t; }
                xwt[((size_t)slot * 64 + s) * G3_ + cg] = f2b(acc[mt][nt][rr] + bias);
            }
    }
}

// ---------------------------------------------------------------------------
// K2: GRU recurrence. 16 WGs x 512 thr (8 waves). WG = {doc|qry} x dir x 16 samples.
// Whh B-fragments register-resident; time-major xw slabs prefetched to regs,
// staged to LDS double-buffer; single barrier per step.
// ---------------------------------------------------------------------------
__global__ __launch_bounds__(512) void k_gru(
    const u16t* __restrict__ xdf, const u16t* __restrict__ xdr,
    const u16t* __restrict__ xqf, const u16t* __restrict__ xqr,
    const u16t* __restrict__ Whh_f, const u16t* __restrict__ Whh_b,
    const float* __restrict__ bhh_f, const float* __restrict__ bhh_b,
    const int* __restrict__ doc_lens, const int* __restrict__ qry_lens,
    u16t* __restrict__ doc_h, u16t* __restrict__ qry_h)
{
    __shared__ u16t hb[2][16][264];     // h state (bf16), dbuf, padded rows
    __shared__ u16t xs[2][16 * G3_];    // staged xw slab (16 samples x 768), dbuf

    const int wid = blockIdx.x;
    const bool isDoc = wid < 8;
    const int local = wid & 7;
    const int dir = local >> 2;
    const int s0 = (local & 3) * 16;
    const int T = isDoc ? TD_ : TQ_;
    const u16t* xwt = isDoc ? (dir ? xdr : xdf) : (dir ? xqr : xqf);
    u16t* outH = isDoc ? doc_h : qry_h;
    const int* lens = isDoc ? doc_lens : qry_lens;
    const u16t* Whh = dir ? Whh_b : Whh_f;
    const float* bhh = dir ? bhh_b : bhh_f;

    const int tid = threadIdx.x;
    const int w = tid >> 6, lane = tid & 63, quad = lane >> 4, l = lane & 15;

    // one-time: B fragments into registers. wave w owns gates j = w*32+jth*16+l
    short8 breg[6][8];
    int cn[6];
#pragma unroll
    for (int nt = 0; nt < 6; ++nt)
        cn[nt] = (nt >> 1) * 256 + w * 32 + (nt & 1) * 16 + l;
#pragma unroll
    for (int nt = 0; nt < 6; ++nt)
#pragma unroll
        for (int kc = 0; kc < 8; ++kc)
            breg[nt][kc] = *(const short8*)(Whh + (size_t)cn[nt] * H_ + kc * 32 + quad * 8);

    float bhn[2];
#pragma unroll
    for (int jth = 0; jth < 2; ++jth) bhn[jth] = bhh[512 + w * 32 + jth * 16 + l];

    int len4[4]; unsigned vo[4];
#pragma unroll
    for (int rr = 0; rr < 4; ++rr) {
        const int sl = quad * 4 + rr;
        len4[rr] = lens[s0 + sl];
        const int pos0 = dir ? (len4[rr] - 1) : 0;
        vo[rr] = (unsigned)((s0 + sl) * T + pos0) * 1024u;   // byte offset of h-row
    }
    const int vdelta = dir ? -1024 : 1024;

    for (int idx = tid; idx < 16 * 264; idx += 512) ((u16t*)hb[0])[idx] = 0;

    // stage slab 0 (24576 B = 3 rounds x 512 thr x 16 B)
    {
        const char* src = (const char*)(xwt + (size_t)s0 * G3_);
        char* dst = (char*)&xs[0][0];
#pragma unroll
        for (int r = 0; r < 3; ++r)
            *(short8*)(dst + r * 8192 + tid * 16) = *(const short8*)(src + r * 8192 + tid * 16);
    }
    float hreg[2][4] = {};
    __syncthreads();

    const size_t slabB = (size_t)64 * G3_ * 2;   // bytes per time-slab (all 64 samples)
    for (int i = 0; i < T; ++i) {
        const int buf = i & 1;

        // prefetch next slab into registers (committed to LDS at end of step)
        short8 pf0, pf1, pf2;
        const bool havenext = (i + 1) < T;
        if (havenext) {
            const char* src = (const char*)xwt + (size_t)(i + 1) * slabB + (size_t)s0 * G3_ * 2;
            pf0 = *(const short8*)(src + tid * 16);
            pf1 = *(const short8*)(src + 8192 + tid * 16);
            pf2 = *(const short8*)(src + 16384 + tid * 16);
        }

        // hh = h @ Whh^T : A from LDS, B from registers
        float4v acc[6] = {};
#pragma unroll
        for (int kc = 0; kc < 8; ++kc) {
            short8 a = *(const short8*)&hb[buf][l][kc * 32 + quad * 8];
#pragma unroll
            for (int nt = 0; nt < 6; ++nt)
                acc[nt] = __builtin_amdgcn_mfma_f32_16x16x32_bf16(a, breg[nt][kc], acc[nt], 0, 0, 0);
        }

        // gates + state update
#pragma unroll
        for (int rr = 0; rr < 4; ++rr) {
            const int sl = quad * 4 + rr;
            const bool valid = i < len4[rr];
            const int xbase = sl * G3_;
#pragma unroll
            for (int jth = 0; jth < 2; ++jth) {
                const int jcol = w * 32 + jth * 16 + l;
                const float gr = b2f(xs[buf][xbase + jcol])       + acc[jth][rr];       // bhh_r folded
                const float gz = b2f(xs[buf][xbase + 256 + jcol]) + acc[2 + jth][rr];   // bhh_z folded
                const float r_ = sigm(gr), z_ = sigm(gz);
                const float nn = tanh_fast(b2f(xs[buf][xbase + 512 + jcol]) +
                                           r_ * (acc[4 + jth][rr] + bhn[jth]));
                const float h = (1.0f - z_) * nn + z_ * hreg[jth][rr];
                hreg[jth][rr] = h;
                const u16t h16 = f2b(h);
                hb[1 - buf][sl][jcol] = h16;
                if (valid)   // byte offset: dir*512 + jcol*2 = dir*512 + w*64 + jth*32 + l*2
                    *(u16t*)((char*)outH + (size_t)vo[rr] + dir * 512 + w * 64 + jth * 32 + l * 2) = h16;
            }
            vo[rr] += (unsigned)vdelta;   // wraps only when stores are predicated off
        }

        // commit prefetched slab to LDS dbuf
        if (havenext) {
            char* dst = (char*)&xs[1 - buf][0];
            *(short8*)(dst + tid * 16) = pf0;
            *(short8*)(dst + 8192 + tid * 16) = pf1;
            *(short8*)(dst + 16384 + tid * 16) = pf2;
        }
        __syncthreads();
    }
}

// ---------------------------------------------------------------------------
// K3: scores[s][d][q] = doc_h[s][d] . qry_h[s][q]  (fp32 out). WG per sample.
// ---------------------------------------------------------------------------
__global__ __launch_bounds__(256) void k_scores(
    const u16t* __restrict__ doc_h, const u16t* __restrict__ qry_h,
    float* __restrict__ scores)
{
    __shared__ u16t qh[32 * 520];   // [q][k] padded
    const int s = blockIdx.x;
    const int tid = threadIdx.x, wave = tid >> 6, lane = tid & 63;
    const int quad = lane >> 4, l = lane & 15;

#pragma unroll
    for (int it = 0; it < 8; ++it) {
        const int v = tid + it * 256;
        const int flat = v * 8, q = flat >> 9, k = flat & 511;
        *(short8*)&qh[q * 520 + k] = *(const short8*)(qry_h + ((size_t)s * TQ_ + q) * HH2_ + k);
    }
    __syncthreads();

    for (int mt = 0; mt < 16; ++mt) {
        const int d0 = wave * 256 + mt * 16;
        float4v a0 = {}, a1 = {};
        const u16t* dp = doc_h + ((size_t)s * TD_ + d0 + l) * HH2_;
#pragma unroll
        for (int kc = 0; kc < 16; ++kc) {
            const int ko = kc * 32 + quad * 8;
            short8 a = *(const short8*)(dp + ko);
            short8 b0 = *(const short8*)&qh[l * 520 + ko];
            short8 b1 = *(const short8*)&qh[(16 + l) * 520 + ko];
            a0 = __builtin_amdgcn_mfma_f32_16x16x32_bf16(a, b0, a0, 0, 0, 0);
            a1 = __builtin_amdgcn_mfma_f32_16x16x32_bf16(a, b1, a1, 0, 0, 0);
        }
        float* sp = scores + ((size_t)s * TD_ + d0) * TQ_;
#pragma unroll
        for (int rr = 0; rr < 4; ++rr) {
            const int d = quad * 4 + rr;
            sp[(size_t)d * TQ_ + l] = a0[rr];
            sp[(size_t)d * TQ_ + 16 + l] = a1[rr];
        }
    }
}

// ---------------------------------------------------------------------------
// K4: per (s,q): amax = max_d scores (raw, incl. exact-0 invalid entries),
//     aden = sum_d exp(sc-amax)*pair_mask + EPS.
// ---------------------------------------------------------------------------
__global__ __launch_bounds__(1024) void k_alpha(
    const float* __restrict__ scores, const int* __restrict__ doc_lens,
    const int* __restrict__ qry_lens, float* __restrict__ amax_g, float* __restrict__ aden_g)
{
    __shared__ float red[32 * 33];
    const int s = blockIdx.x, tid = threadIdx.x;
    const int q = tid & 31, dg = tid >> 5;
    const float* sp = scores + (size_t)s * TD_ * TQ_;

    float m = -1e30f;
#pragma unroll 4
    for (int k = 0; k < 32; ++k) m = fmaxf(m, sp[(size_t)(dg + k * 32) * TQ_ + q]);
    red[q * 33 + dg] = m; __syncthreads();
    for (int off = 16; off > 0; off >>= 1) {
        if (dg < off) red[q * 33 + dg] = fmaxf(red[q * 33 + dg], red[q * 33 + dg + off]);
        __syncthreads();
    }
    const float mx = red[q * 33];
    __syncthreads();

    const int dlen = doc_lens[s], qlen = qry_lens[s];
    float sum = 0.0f;
    if (q < qlen) {
#pragma unroll 4
        for (int k = 0; k < 32; ++k) {
            const int d = dg + k * 32;
            if (d < dlen) sum += __expf(sp[(size_t)d * TQ_ + q] - mx);
        }
    }
    red[q * 33 + dg] = sum; __syncthreads();
    for (int off = 16; off > 0; off >>= 1) {
        if (dg < off) red[q * 33 + dg] += red[q * 33 + dg + off];
        __syncthreads();
    }
    if (dg == 0) {
        amax_g[s * 32 + q] = mx;
        aden_g[s * 32 + q] = red[q * 33] + 1e-12f;
    }
}

// ---------------------------------------------------------------------------
// K5: beta softmax (axis=q), beta_aver, s_d, probs (fp32 out[s]), vocab scatter.
// ---------------------------------------------------------------------------
__global__ __launch_bounds__(1024) void k_attn(
    const float* __restrict__ scores, const int* __restrict__ documents,
    const int* __restrict__ doc_lens, const int* __restrict__ qry_lens,
    const int* __restrict__ answers,
    const float* __restrict__ amax_g, const float* __restrict__ aden_g,
    float* __restrict__ wordbuf, float* __restrict__ out_f)
{
    __shared__ float l_amax[32], l_aden[32], l_ba[32];
    __shared__ float l_probs;
    const int s = blockIdx.x, d = threadIdx.x;
    if (d < 32) { l_amax[d] = amax_g[s * 32 + d]; l_aden[d] = aden_g[s * 32 + d]; l_ba[d] = 0.0f; }
    if (d == 0) l_probs = 0.0f;
    __syncthreads();

    const int dlen = doc_lens[s], qlen = qry_lens[s];
    const bool maskd = d < dlen;
    float raw[32];
    const float* sp = scores + ((size_t)s * TD_ + d) * TQ_;
#pragma unroll
    for (int q = 0; q < 32; q += 4) {
        float4v v = *(const float4v*)(sp + q);
        raw[q] = v[0]; raw[q + 1] = v[1]; raw[q + 2] = v[2]; raw[q + 3] = v[3];
    }
    float rowmax = raw[0];
#pragma unroll
    for (int q = 1; q < 32; ++q) rowmax = fmaxf(rowmax, raw[q]);

    float den = 1e-12f;
    if (maskd)
        for (int q = 0; q < qlen; ++q) den += __expf(raw[q] - rowmax);

#pragma unroll
    for (int q = 0; q < 32; ++q) {
        float beta = (maskd && q < qlen) ? __expf(raw[q] - rowmax) / den : 0.0f;
#pragma unroll
        for (int off = 1; off < 64; off <<= 1) beta += __shfl_xor(beta, off);
        if ((threadIdx.x & 63) == 0 && beta != 0.0f) atomicAdd(&l_ba[q], beta);
    }
    __syncthreads();

    float sd = 0.0f;
    if (maskd) {
        const float inv_dlen = 1.0f / (float)dlen;
        for (int q = 0; q < qlen; ++q) {
            const float ae = __expf(raw[q] - l_amax[q]) / l_aden[q];
            sd += ae * (l_ba[q] * inv_dlen);
        }
    }
    const int tok = documents[s * TD_ + d];
    float p = (tok == answers[s]) ? sd : 0.0f;
#pragma unroll
    for (int off = 1; off < 64; off <<= 1) p += __shfl_xor(p, off);
    if ((threadIdx.x & 63) == 0 && p != 0.0f) atomicAdd(&l_probs, p);
    if (maskd && sd != 0.0f) atomicAdd(wordbuf + (size_t)s * V_ + tok, sd);
    __syncthreads();
    if (threadIdx.x == 0) out_f[s] = l_probs;
}

// ---------------------------------------------------------------------------
// K6: per-sample argmax over vocab; fp32 index to out[64+s]. Lowest-idx ties.
// ---------------------------------------------------------------------------
__global__ __launch_bounds__(256) void k_argmax(
    const float* __restrict__ wordbuf, float* __restrict__ out_f)
{
    __shared__ float bv[256];
    __shared__ int bi[256];
    const int s = blockIdx.x, tid = threadIdx.x;
    const float* wp = wordbuf + (size_t)s * V_;
    float best = -1e30f; int bidx = 0;
    for (int v = tid; v < V_; v += 256) {
        const float f = wp[v];
        if (f > best) { best = f; bidx = v; }
    }
    bv[tid] = best; bi[tid] = bidx; __syncthreads();
    for (int off = 128; off > 0; off >>= 1) {
        if (tid < off) {
            const float fo = bv[tid + off]; const int io = bi[tid + off];
            if (fo > bv[tid] || (fo == bv[tid] && io < bi[tid])) { bv[tid] = fo; bi[tid] = io; }
        }
        __syncthreads();
    }
    if (tid == 0) out_f[64 + s] = (float)bi[0];
}

// ---------------------------------------------------------------------------
// Workspace (peak 277.6 MB):
//   Whh_f16/b16 | hblock{doc_h+qry_h; early alias emb+Wih} |
//   xwt_qry_f/r | xwt_doc_f{late alias scores/amax/aden/wordbuf} | xwt_doc_r
// ---------------------------------------------------------------------------
extern "C" void kernel_launch(void* const* d_in, const int* in_sizes, int n_in,
                              void* d_out, int out_size, void* d_ws, size_t ws_size,
                              hipStream_t stream)
{
    const int*   documents  = (const int*)d_in[0];
    const int*   doc_lens   = (const int*)d_in[1];
    const int*   querys     = (const int*)d_in[2];
    const int*   query_lens = (const int*)d_in[3];
    const int*   answers    = (const int*)d_in[4];
    const float* emb_f32    = (const float*)d_in[5];
    const float* Wih_f_f32  = (const float*)d_in[6];
    const float* Whh_f_f32  = (const float*)d_in[7];
    const float* bih_f      = (const float*)d_in[8];
    const float* bhh_f      = (const float*)d_in[9];
    const float* Wih_b_f32  = (const float*)d_in[10];
    const float* Whh_b_f32  = (const float*)d_in[11];
    const float* bih_b      = (const float*)d_in[12];
    const float* bhh_b      = (const float*)d_in[13];
    float* out = (float*)d_out;   // fp32: [probs(64), pred_answers(64)]
    char* ws = (char*)d_ws;

    size_t o = 0;
    u16t* Whh_f16 = (u16t*)(ws + o); o += (size_t)G3_ * H_ * 2;
    u16t* Whh_b16 = (u16t*)(ws + o); o += (size_t)G3_ * H_ * 2;
    char* hblock = ws + o;
    u16t* doc_h = (u16t*)(ws + o); o += (size_t)B_ * TD_ * HH2_ * 2;     //  67.1 MB
    u16t* qry_h = (u16t*)(ws + o); o += (size_t)B_ * TQ_ * HH2_ * 2;     //   2.1 MB
    const size_t hbytes = (size_t)(ws + o - hblock);
    u16t* xwt_qry_f = (u16t*)(ws + o); o += (size_t)TQ_ * B_ * G3_ * 2;  //   3.1 MB
    u16t* xwt_qry_r = (u16t*)(ws + o); o += (size_t)TQ_ * B_ * G3_ * 2;  //   3.1 MB
    char* xdblock = ws + o;
    u16t* xwt_doc_f = (u16t*)(ws + o); o += (size_t)TD_ * B_ * G3_ * 2;  // 100.7 MB
    u16t* xwt_doc_r = (u16t*)(ws + o); o += (size_t)TD_ * B_ * G3_ * 2;  // 100.7 MB
    const size_t total = o;                                              // 277.6 MB
    if (ws_size < total) return;

    // early aliases (dead once k_xw completes): emb/Wih bf16 inside hblock
    u16t* emb_b16   = (u16t*)hblock;
    u16t* Wih_f16   = (u16t*)(hblock + (size_t)V_ * E_ * 2);
    u16t* Wih_b16   = Wih_f16 + (size_t)G3_ * E_;
    // late aliases (live once xwt_doc_f is dead, i.e. after k_gru):
    float* scores  = (float*)xdblock;
    float* amax    = (float*)(xdblock + (size_t)B_ * TD_ * TQ_ * 4);
    float* aden    = amax + B_ * 32;
    float* wordbuf = aden + B_ * 32;

    // 1) fp32 -> bf16 conversions
    const int n_emb4 = V_ * E_ / 4, n_wih4 = G3_ * E_ / 4, n_whh4 = G3_ * H_ / 4;
    k_f2b<<<(n_emb4 + 255) / 256, 256, 0, stream>>>(emb_f32, emb_b16, n_emb4);
    k_f2b<<<(n_wih4 + 255) / 256, 256, 0, stream>>>(Wih_f_f32, Wih_f16, n_wih4);
    k_f2b<<<(n_wih4 + 255) / 256, 256, 0, stream>>>(Wih_b_f32, Wih_b16, n_wih4);
    k_f2b<<<(n_whh4 + 255) / 256, 256, 0, stream>>>(Whh_f_f32, Whh_f16, n_whh4);
    k_f2b<<<(n_whh4 + 255) / 256, 256, 0, stream>>>(Whh_b_f32, Whh_b16, n_whh4);

    // 2) input projections (time-major, bwd pre-reversed, bhh_r/z folded)
    k_xw<<<dim3(12, (B_ * TD_) / 64), 256, 0, stream>>>(documents, emb_b16, Wih_f16, Wih_b16,
        bih_f, bih_b, bhh_f, bhh_b, doc_lens, 10, xwt_doc_f, xwt_doc_r);
    k_xw<<<dim3(12, (B_ * TQ_) / 64), 256, 0, stream>>>(querys, emb_b16, Wih_f16, Wih_b16,
        bih_f, bih_b, bhh_f, bhh_b, query_lens, 5, xwt_qry_f, xwt_qry_r);

    // 3) alias dead: zero doc_h/qry_h (invalid positions must be exactly 0)
    hipMemsetAsync(hblock, 0, hbytes, stream);

    // 4) recurrence
    k_gru<<<16, 512, 0, stream>>>(xwt_doc_f, xwt_doc_r, xwt_qry_f, xwt_qry_r,
                                  Whh_f16, Whh_b16, bhh_f, bhh_b,
                                  doc_lens, query_lens, doc_h, qry_h);

    // 5) xwt_doc_f dead: zero wordbuf alias, then attention chain
    hipMemsetAsync(wordbuf, 0, (size_t)B_ * V_ * 4, stream);
    k_scores<<<B_, 256, 0, stream>>>(doc_h, qry_h, scores);
    k_alpha<<<B_, 1024, 0, stream>>>(scores, doc_lens, query_lens, amax, aden);
    k_attn<<<B_, 1024, 0, stream>>>(scores, documents, doc_lens, query_lens, answers,
                                    amax, aden, wordbuf, out);
    k_argmax<<<B_, 256, 0, stream>>>(wordbuf, out);
}